// Round 8
// baseline (434.121 us; speedup 1.0000x reference)
//
#include <hip/hip_runtime.h>
#include <hip/hip_bf16.h>
#include <stdint.h>

#define VOCAB 17346050
#define EMB 2
#define SEQ 3335
#define BATCH 4096
#define BLOCK 256

// Native clang vector type — __builtin_nontemporal_load requires it
// (HIP's int4 is a class and is rejected).
typedef int int4v __attribute__((ext_vector_type(4)));

// One block per batch row.
// table:   [VOCAB][2] fp32   (139 MB, hot: keep in L3)
// conv_w:  [2][SEQ]   fp32   (26.7 KB, hot)
// dense_w: [2]        fp32
// idx:     [BATCH][SEQ] int32 (54.6 MB, streamed once: nontemporal)
// out:     [BATCH]    fp32
__global__ __launch_bounds__(BLOCK) void mlp_fused_kernel(
    const float* __restrict__ table,
    const float* __restrict__ conv_w,
    const float* __restrict__ dense_w,
    const int* __restrict__ idx,
    float* __restrict__ out)
{
    const int b = blockIdx.x;
    const int tid = threadIdx.x;
    const int* __restrict__ row = idx + (size_t)b * (size_t)SEQ;

    // Row base is not 16B-aligned in general (SEQ*4 = 13340 B, 13340 % 16 = 12).
    // Scalar prologue up to 16B boundary, then int4 main loop, scalar tail.
    const int mis = (int)(((uintptr_t)row >> 2) & 3);  // ints past a 16B boundary
    const int pro = (4 - mis) & 3;                     // scalar prologue count (0..3)
    const int nvec = (SEQ - pro) >> 2;                 // int4 groups
    const int tail_start = pro + (nvec << 2);
    const int tail_cnt = SEQ - tail_start;             // 0..3

    float acc0 = 0.0f, acc1 = 0.0f;

    if (tid < pro) {
        const int l = tid;
        const unsigned v = (unsigned)row[l];
        const float2 e = *(const float2*)(table + (size_t)v * 2u);
        acc0 = fmaf(e.x, conv_w[l], acc0);
        acc1 = fmaf(e.y, conv_w[SEQ + l], acc1);
    }
    if (tid < tail_cnt) {
        const int l = tail_start + tid;
        const unsigned v = (unsigned)row[l];
        const float2 e = *(const float2*)(table + (size_t)v * 2u);
        acc0 = fmaf(e.x, conv_w[l], acc0);
        acc1 = fmaf(e.y, conv_w[SEQ + l], acc1);
    }

    const int4v* __restrict__ row4 = (const int4v*)(row + pro);

    // Main loop: 2 int4 groups per thread per iteration -> 8 independent
    // gathers in flight (latency-bound workload; maximize memory-level
    // parallelism). Index loads are nontemporal: streamed once, keep L3
    // capacity for the table.
    int i = tid * 2;
    const int stride = BLOCK * 2;
    for (; i + 1 < nvec; i += stride) {
        const int4v va = __builtin_nontemporal_load(row4 + i);
        const int4v vb = __builtin_nontemporal_load(row4 + i + 1);
        const int l = pro + (i << 2);
        const float2 e0 = *(const float2*)(table + (size_t)(unsigned)va.x * 2u);
        const float2 e1 = *(const float2*)(table + (size_t)(unsigned)va.y * 2u);
        const float2 e2 = *(const float2*)(table + (size_t)(unsigned)va.z * 2u);
        const float2 e3 = *(const float2*)(table + (size_t)(unsigned)va.w * 2u);
        const float2 e4 = *(const float2*)(table + (size_t)(unsigned)vb.x * 2u);
        const float2 e5 = *(const float2*)(table + (size_t)(unsigned)vb.y * 2u);
        const float2 e6 = *(const float2*)(table + (size_t)(unsigned)vb.z * 2u);
        const float2 e7 = *(const float2*)(table + (size_t)(unsigned)vb.w * 2u);
        const float* __restrict__ c0 = conv_w + l;
        const float* __restrict__ c1 = conv_w + SEQ + l;
        acc0 = fmaf(e0.x, c0[0], acc0);
        acc0 = fmaf(e1.x, c0[1], acc0);
        acc0 = fmaf(e2.x, c0[2], acc0);
        acc0 = fmaf(e3.x, c0[3], acc0);
        acc0 = fmaf(e4.x, c0[4], acc0);
        acc0 = fmaf(e5.x, c0[5], acc0);
        acc0 = fmaf(e6.x, c0[6], acc0);
        acc0 = fmaf(e7.x, c0[7], acc0);
        acc1 = fmaf(e0.y, c1[0], acc1);
        acc1 = fmaf(e1.y, c1[1], acc1);
        acc1 = fmaf(e2.y, c1[2], acc1);
        acc1 = fmaf(e3.y, c1[3], acc1);
        acc1 = fmaf(e4.y, c1[4], acc1);
        acc1 = fmaf(e5.y, c1[5], acc1);
        acc1 = fmaf(e6.y, c1[6], acc1);
        acc1 = fmaf(e7.y, c1[7], acc1);
    }
    // Odd leftover int4 group (nvec may be odd).
    if (i < nvec) {
        const int4v v = __builtin_nontemporal_load(row4 + i);
        const int l = pro + (i << 2);
        const float2 e0 = *(const float2*)(table + (size_t)(unsigned)v.x * 2u);
        const float2 e1 = *(const float2*)(table + (size_t)(unsigned)v.y * 2u);
        const float2 e2 = *(const float2*)(table + (size_t)(unsigned)v.z * 2u);
        const float2 e3 = *(const float2*)(table + (size_t)(unsigned)v.w * 2u);
        const float* __restrict__ c0 = conv_w + l;
        const float* __restrict__ c1 = conv_w + SEQ + l;
        acc0 = fmaf(e0.x, c0[0], acc0);
        acc0 = fmaf(e1.x, c0[1], acc0);
        acc0 = fmaf(e2.x, c0[2], acc0);
        acc0 = fmaf(e3.x, c0[3], acc0);
        acc1 = fmaf(e0.y, c1[0], acc1);
        acc1 = fmaf(e1.y, c1[1], acc1);
        acc1 = fmaf(e2.y, c1[2], acc1);
        acc1 = fmaf(e3.y, c1[3], acc1);
    }

    // Wave-level reduction (64 lanes).
    #pragma unroll
    for (int off = 32; off > 0; off >>= 1) {
        acc0 += __shfl_down(acc0, off, 64);
        acc1 += __shfl_down(acc1, off, 64);
    }

    __shared__ float s0[BLOCK / 64];
    __shared__ float s1[BLOCK / 64];
    const int wave = tid >> 6;
    const int lane = tid & 63;
    if (lane == 0) { s0[wave] = acc0; s1[wave] = acc1; }
    __syncthreads();

    if (tid == 0) {
        const float w0 = dense_w[0];
        const float w1 = dense_w[1];
        float x0 = s0[0] + s0[1] + s0[2] + s0[3];
        float x1 = s1[0] + s1[1] + s1[2] + s1[3];
        // hardswish: x * clip(x+3, 0, 6) / 6
        x0 = x0 * fminf(fmaxf(x0 + 3.0f, 0.0f), 6.0f) * (1.0f / 6.0f);
        x1 = x1 * fminf(fmaxf(x1 + 3.0f, 0.0f), 6.0f) * (1.0f / 6.0f);
        const float y = fmaf(x0, w0, x1 * w1);
        __builtin_nontemporal_store(tanhf(y), out + b);
    }
}

extern "C" void kernel_launch(void* const* d_in, const int* in_sizes, int n_in,
                              void* d_out, int out_size, void* d_ws, size_t ws_size,
                              hipStream_t stream) {
    const float* table   = (const float*)d_in[0];
    const float* conv_w  = (const float*)d_in[1];
    const float* dense_w = (const float*)d_in[2];
    const int*   idx     = (const int*)d_in[3];
    float*       out     = (float*)d_out;

    mlp_fused_kernel<<<BATCH, BLOCK, 0, stream>>>(table, conv_w, dense_w, idx, out);
}